// Round 1
// baseline (1810.865 us; speedup 1.0000x reference)
//
#include <hip/hip_runtime.h>
#include <hip/hip_bf16.h>

// Problem constants
#define BB   2
#define CC   256
#define PCC  256
#define OCC  256
#define HH   128
#define WW   128
#define NHH  4
#define DDIM 64
#define N2   4096    // 64*64 attn pixels
#define HWP  16384   // 128*128
#define EPSI 1e-5f

// ---- workspace layout (float offsets) ----
// Phase 1-3: q,k,v,att,S live. Phase 4-5: y3 (aliases q/k/v/att), sums (alias S).
static const size_t Q_OFF    = 0;          // 2,097,152  [B][256][4096]
static const size_t K_OFF    = 2097152;    // 2,097,152
static const size_t V_OFF    = 4194304;    // 2,097,152
static const size_t ATT_OFF  = 6291456;    // 2,097,152
static const size_t S_OFF    = 8388608;    // 32,768  St[bh][d'][d]
static const size_t SUM_OFF  = 8388608;    // 1024 (aliases S after attn done)
static const size_t SUM2_OFF = 8389632;    // 1024
static const size_t Y3_OFF   = 0;          // 8,388,608 (aliases q/k/v/att)
static const size_t X1_OFF   = 8421376;    // 8,388,608  [B][256][16384]
static const size_t QWT_OFF  = 16809984;   // 262,144  wT[k][oc]
static const size_t KWT_OFF  = 17072128;
static const size_t VWT_OFF  = 17334272;
static const size_t FWT_OFF  = 17596416;   // 131,072
static const size_t CWT_OFF  = 17727488;   // 1,179,648
// end = 18,907,136 floats = 75.6 MB

// ---------------- weight transpose: wT[k][oc] = w[oc][k] ----------------
__global__ __launch_bounds__(256) void transpose_w(const float* __restrict__ w,
                                                   float* __restrict__ wT,
                                                   int M, int K) {
    int total = M * K;
    for (int idx = blockIdx.x * 256 + threadIdx.x; idx < total; idx += gridDim.x * 256) {
        int oc = idx / K, k = idx - oc * K;
        wT[k * M + oc] = w[idx];
    }
}

// 16-step K-chunk FMA micro-kernel: acc[4][4] += As[kk][ty*4+i]*Bs[kk][tx*4+j]
__device__ __forceinline__ void mm16(const float (*As)[64], const float (*Bs)[64],
                                     int ty, int tx, float acc[4][4]) {
#pragma unroll
    for (int kk = 0; kk < 16; ++kk) {
        float4 a4 = *(const float4*)&As[kk][ty * 4];
        float4 b4 = *(const float4*)&Bs[kk][tx * 4];
        float a[4] = {a4.x, a4.y, a4.z, a4.w};
        float b[4] = {b4.x, b4.y, b4.z, b4.w};
#pragma unroll
        for (int i = 0; i < 4; ++i)
#pragma unroll
            for (int j = 0; j < 4; ++j)
                acc[i][j] = fmaf(a[i], b[j], acc[i][j]);
    }
}

// ---------------- q/k/v stride-2 2x2 conv as GEMM ----------------
// grid (64 pixel-rows, 4 oc-tiles, 6 = b*3+conv); out[b][oc][n], n = y2*64+x2
__global__ __launch_bounds__(256) void qkv_conv(
    const float* __restrict__ pose, const float* __restrict__ app_pose,
    const float* __restrict__ app,
    const float* __restrict__ qb, const float* __restrict__ kb,
    const float* __restrict__ vb, float* __restrict__ ws)
{
    int y2 = blockIdx.x;          // output row (w2 = 64 -> 64-px tile = one row)
    int oc0 = blockIdx.y * 64;
    int z = blockIdx.z;
    int b = z / 3, conv = z % 3;
    const float* in   = conv == 0 ? pose : (conv == 1 ? app_pose : app);
    const float* wT   = ws + (conv == 0 ? QWT_OFF : (conv == 1 ? KWT_OFF : VWT_OFF));
    const float* bias = conv == 0 ? qb : (conv == 1 ? kb : vb);
    float* out        = ws + (conv == 0 ? Q_OFF : (conv == 1 ? K_OFF : V_OFF));

    __shared__ float As[16][64];
    __shared__ float Bs[16][64];
    int t = threadIdx.x, ty = t >> 4, tx = t & 15;
    const float* inb = in + (size_t)b * CC * HH * WW;
    float acc[4][4] = {};

    for (int k0 = 0; k0 < 1024; k0 += 16) {
#pragma unroll
        for (int i = 0; i < 4; ++i) {
            int idx = t + i * 256;
            int kk = idx >> 6, ocl = idx & 63;
            As[kk][ocl] = wT[(size_t)(k0 + kk) * 256 + oc0 + ocl];
        }
#pragma unroll
        for (int i = 0; i < 4; ++i) {
            int idx = t + i * 256;
            int kk = idx >> 6, j = idx & 63;
            int k = k0 + kk;
            int c = k >> 2, fy = (k >> 1) & 1, fx = k & 1;
            Bs[kk][j] = inb[((size_t)c * HH + (2 * y2 + fy)) * WW + 2 * j + fx];
        }
        __syncthreads();
        mm16(As, Bs, ty, tx, acc);
        __syncthreads();
    }
#pragma unroll
    for (int i = 0; i < 4; ++i) {
        int oc = oc0 + ty * 4 + i;
        float bv = bias[oc];
        float4 r;
        r.x = acc[i][0] + bv; r.y = acc[i][1] + bv;
        r.z = acc[i][2] + bv; r.w = acc[i][3] + bv;
        *(float4*)&out[((size_t)b * 256 + oc) * N2 + y2 * 64 + tx * 4] = r;
    }
}

// ---------------- St[d'][d] = sum_m v[d,m]*k[d',m] (factored attention) ----
// grid (8 m-chunks, 8 bh); atomicAdd partials into zeroed S
__global__ __launch_bounds__(256) void attn_S_k(float* __restrict__ ws)
{
    int mc = blockIdx.x;
    int bh = blockIdx.y;
    int b = bh >> 2, h = bh & 3;
    const float* vp = ws + V_OFF + (size_t)(b * 256 + h * 64) * N2;
    const float* kp = ws + K_OFF + (size_t)(b * 256 + h * 64) * N2;
    float* Sp = ws + S_OFF + (size_t)bh * 4096;

    __shared__ float VsT[16][64];
    __shared__ float KsT[16][64];
    int t = threadIdx.x, ty = t >> 4, tx = t & 15;
    int d_ = t >> 2;      // 0..63
    int mg = t & 3;       // 0..3 (float4 group)
    float acc[4][4] = {};

    for (int m0 = mc * 512; m0 < mc * 512 + 512; m0 += 16) {
        float4 v4 = *(const float4*)&vp[(size_t)d_ * N2 + m0 + mg * 4];
        float4 k4 = *(const float4*)&kp[(size_t)d_ * N2 + m0 + mg * 4];
        VsT[mg * 4 + 0][d_] = v4.x; VsT[mg * 4 + 1][d_] = v4.y;
        VsT[mg * 4 + 2][d_] = v4.z; VsT[mg * 4 + 3][d_] = v4.w;
        KsT[mg * 4 + 0][d_] = k4.x; KsT[mg * 4 + 1][d_] = k4.y;
        KsT[mg * 4 + 2][d_] = k4.z; KsT[mg * 4 + 3][d_] = k4.w;
        __syncthreads();
        mm16(VsT, KsT, ty, tx, acc);   // i -> d (V), j -> d' (K)
        __syncthreads();
    }
#pragma unroll
    for (int i = 0; i < 4; ++i)
#pragma unroll
        for (int j = 0; j < 4; ++j)
            atomicAdd(&Sp[(tx * 4 + j) * 64 + (ty * 4 + i)], acc[i][j]);
}

// ---------------- attn out: att[d][n] = gamma/8 * sum_d' St[d'][d] q[d'][n] --
// grid (64 n-tiles, 8 bh)
__global__ __launch_bounds__(256) void attn_O_k(const float* __restrict__ gamma,
                                                float* __restrict__ ws)
{
    int n0 = blockIdx.x * 64;
    int bh = blockIdx.y;
    int b = bh >> 2, h = bh & 3;
    const float* Sp = ws + S_OFF + (size_t)bh * 4096;
    const float* qp = ws + Q_OFF + (size_t)(b * 256 + h * 64) * N2;
    float* op = ws + ATT_OFF + (size_t)(b * 256 + h * 64) * N2;
    float scale = gamma[h] * 0.125f;   // 1/sqrt(64)

    __shared__ float STs[64][64];   // St[d'][d]
    __shared__ float Qs[16][64];
    int t = threadIdx.x, ty = t >> 4, tx = t & 15;
#pragma unroll
    for (int i = 0; i < 16; ++i) {
        int idx = t + i * 256;
        STs[idx >> 6][idx & 63] = Sp[idx];
    }
    float acc[4][4] = {};
    for (int d0 = 0; d0 < 64; d0 += 16) {
#pragma unroll
        for (int i = 0; i < 4; ++i) {
            int idx = t + i * 256;
            int dd = idx >> 6, j = idx & 63;
            Qs[dd][j] = qp[(size_t)(d0 + dd) * N2 + n0 + j];
        }
        __syncthreads();
#pragma unroll
        for (int dd = 0; dd < 16; ++dd) {
            float4 a4 = *(const float4*)&STs[d0 + dd][ty * 4];
            float4 q4 = *(const float4*)&Qs[dd][tx * 4];
            float a[4] = {a4.x, a4.y, a4.z, a4.w};
            float q[4] = {q4.x, q4.y, q4.z, q4.w};
#pragma unroll
            for (int i = 0; i < 4; ++i)
#pragma unroll
                for (int j = 0; j < 4; ++j)
                    acc[i][j] = fmaf(a[i], q[j], acc[i][j]);
        }
        __syncthreads();
    }
#pragma unroll
    for (int i = 0; i < 4; ++i) {
        float4 r;
        r.x = scale * acc[i][0]; r.y = scale * acc[i][1];
        r.z = scale * acc[i][2]; r.w = scale * acc[i][3];
        *(float4*)&op[(size_t)(ty * 4 + i) * N2 + n0 + tx * 4] = r;
    }
}

// ---------------- 1x1 conv over [pose ; upsampled att] ----------------
// grid (256 px-tiles, 4 oc-tiles, 2 b); x1[b][oc][p]
__global__ __launch_bounds__(256) void conv1x1_k(const float* __restrict__ pose,
                                                 const float* __restrict__ fb,
                                                 float* __restrict__ ws)
{
    int p0 = blockIdx.x * 64;
    int oc0 = blockIdx.y * 64;
    int b = blockIdx.z;
    int y = p0 >> 7, x0 = p0 & 127;
    const float* fwT = ws + FWT_OFF;
    const float* att = ws + ATT_OFF + (size_t)b * CC * N2;
    const float* pz  = pose + (size_t)b * CC * HWP;
    float* out = ws + X1_OFF + (size_t)b * CC * HWP;

    __shared__ float As[16][64];
    __shared__ float Bs[16][64];
    int t = threadIdx.x, ty = t >> 4, tx = t & 15;
    float acc[4][4] = {};

    for (int k0 = 0; k0 < 512; k0 += 16) {
#pragma unroll
        for (int i = 0; i < 4; ++i) {
            int idx = t + i * 256;
            int kk = idx >> 6, ocl = idx & 63;
            As[kk][ocl] = fwT[(size_t)(k0 + kk) * 256 + oc0 + ocl];
        }
#pragma unroll
        for (int i = 0; i < 4; ++i) {
            int idx = t + i * 256;
            int kk = idx >> 6, j = idx & 63;
            int k = k0 + kk;
            float v;
            if (k < 256) v = pz[(size_t)k * HWP + y * 128 + x0 + j];
            else         v = att[(size_t)(k - 256) * N2 + (y >> 1) * 64 + ((x0 + j) >> 1)];
            Bs[kk][j] = v;
        }
        __syncthreads();
        mm16(As, Bs, ty, tx, acc);
        __syncthreads();
    }
#pragma unroll
    for (int i = 0; i < 4; ++i) {
        int oc = oc0 + ty * 4 + i;
        float bv = fb[oc];
        float4 r;
        r.x = acc[i][0] + bv; r.y = acc[i][1] + bv;
        r.z = acc[i][2] + bv; r.w = acc[i][3] + bv;
        *(float4*)&out[(size_t)oc * HWP + y * 128 + x0 + tx * 4] = r;
    }
}

// ---------------- 3x3 SAME conv over [x1 ; upsampled prev] + IN partial sums --
// grid (256 px-tiles, 4 oc-tiles, 2 b)
__global__ __launch_bounds__(256) void conv3x3_k(const float* __restrict__ prev,
                                                 const float* __restrict__ cb,
                                                 float* __restrict__ ws)
{
    int p0 = blockIdx.x * 64;
    int oc0 = blockIdx.y * 64;
    int b = blockIdx.z;
    int y = p0 >> 7, x0 = p0 & 127;
    const float* cwT = ws + CWT_OFF;
    const float* x1 = ws + X1_OFF + (size_t)b * CC * HWP;
    const float* pv = prev + (size_t)b * PCC * N2;
    float* yo  = ws + Y3_OFF + (size_t)b * OCC * HWP;
    float* gs  = ws + SUM_OFF;
    float* gs2 = ws + SUM2_OFF;

    __shared__ float As[16][64];
    __shared__ float Bs[16][64];
    __shared__ float ls[64], ls2[64];
    int t = threadIdx.x, ty = t >> 4, tx = t & 15;
    float acc[4][4] = {};

    for (int k0 = 0; k0 < 4608; k0 += 16) {
#pragma unroll
        for (int i = 0; i < 4; ++i) {
            int idx = t + i * 256;
            int kk = idx >> 6, ocl = idx & 63;
            As[kk][ocl] = cwT[(size_t)(k0 + kk) * 256 + oc0 + ocl];
        }
#pragma unroll
        for (int i = 0; i < 4; ++i) {
            int idx = t + i * 256;
            int kk = idx >> 6, j = idx & 63;
            int k = k0 + kk;
            int c = k / 9;
            int r = k - c * 9;
            int fy = r / 3, fx = r - fy * 3;
            int yy = y + fy - 1, xx = x0 + j + fx - 1;
            float v = 0.f;
            if (yy >= 0 && yy < 128 && xx >= 0 && xx < 128) {
                if (c < 256) v = x1[(size_t)c * HWP + yy * 128 + xx];
                else         v = pv[(size_t)(c - 256) * N2 + (yy >> 1) * 64 + (xx >> 1)];
            }
            Bs[kk][j] = v;
        }
        __syncthreads();
        mm16(As, Bs, ty, tx, acc);
        __syncthreads();
    }

    if (t < 64) { ls[t] = 0.f; ls2[t] = 0.f; }
    __syncthreads();
#pragma unroll
    for (int i = 0; i < 4; ++i) {
        int ocl = ty * 4 + i;
        int oc = oc0 + ocl;
        float bv = cb[oc];
        float vals[4];
        float rs = 0.f, rs2 = 0.f;
#pragma unroll
        for (int j = 0; j < 4; ++j) {
            float v = acc[i][j] + bv;
            vals[j] = v; rs += v; rs2 += v * v;
        }
        float4 r; r.x = vals[0]; r.y = vals[1]; r.z = vals[2]; r.w = vals[3];
        *(float4*)&yo[(size_t)oc * HWP + y * 128 + x0 + tx * 4] = r;
        atomicAdd(&ls[ocl], rs);
        atomicAdd(&ls2[ocl], rs2);
    }
    __syncthreads();
    if (t < 64) {
        atomicAdd(&gs[b * 256 + oc0 + t], ls[t]);
        atomicAdd(&gs2[b * 256 + oc0 + t], ls2[t]);
    }
}

// ---------------- instance norm + relu -> f32 out ----------------
__global__ __launch_bounds__(256) void inorm_relu_k(const float* __restrict__ ws,
                                                    float* __restrict__ out)
{
    int bc = blockIdx.x;   // b*256+oc
    const float* yp = ws + Y3_OFF + (size_t)bc * HWP;
    float mean = ws[SUM_OFF + bc] * (1.0f / HWP);
    float var  = ws[SUM2_OFF + bc] * (1.0f / HWP) - mean * mean;
    float inv = rsqrtf(var + EPSI);
    float* op = out + (size_t)bc * HWP;
    int t = threadIdx.x;
#pragma unroll
    for (int i = 0; i < 16; ++i) {
        int p = (i * 256 + t) * 4;
        float4 v = *(const float4*)&yp[p];
        float4 r;
        r.x = fmaxf((v.x - mean) * inv, 0.f);
        r.y = fmaxf((v.y - mean) * inv, 0.f);
        r.z = fmaxf((v.z - mean) * inv, 0.f);
        r.w = fmaxf((v.w - mean) * inv, 0.f);
        *(float4*)&op[p] = r;
    }
}

extern "C" void kernel_launch(void* const* d_in, const int* in_sizes, int n_in,
                              void* d_out, int out_size, void* d_ws, size_t ws_size,
                              hipStream_t stream)
{
    (void)in_sizes; (void)n_in; (void)out_size; (void)ws_size;
    const float* app_enc  = (const float*)d_in[0];
    const float* app_pose = (const float*)d_in[1];
    const float* pose_enc = (const float*)d_in[2];
    const float* prev_inp = (const float*)d_in[3];
    const float* qw = (const float*)d_in[4];
    const float* qb = (const float*)d_in[5];
    const float* kw = (const float*)d_in[6];
    const float* kb = (const float*)d_in[7];
    const float* vw = (const float*)d_in[8];
    const float* vb = (const float*)d_in[9];
    const float* gamma = (const float*)d_in[10];
    const float* fw = (const float*)d_in[11];
    const float* fb = (const float*)d_in[12];
    const float* cw = (const float*)d_in[13];
    const float* cb = (const float*)d_in[14];
    float* ws  = (float*)d_ws;
    float* out = (float*)d_out;

    // weight transposes: wT[k][oc]
    hipLaunchKernelGGL(transpose_w, dim3(512), dim3(256), 0, stream, qw, ws + QWT_OFF, 256, 1024);
    hipLaunchKernelGGL(transpose_w, dim3(512), dim3(256), 0, stream, kw, ws + KWT_OFF, 256, 1024);
    hipLaunchKernelGGL(transpose_w, dim3(512), dim3(256), 0, stream, vw, ws + VWT_OFF, 256, 1024);
    hipLaunchKernelGGL(transpose_w, dim3(512), dim3(256), 0, stream, fw, ws + FWT_OFF, 256, 512);
    hipLaunchKernelGGL(transpose_w, dim3(512), dim3(256), 0, stream, cw, ws + CWT_OFF, 256, 4608);

    // q/k/v projections
    hipLaunchKernelGGL(qkv_conv, dim3(64, 4, 6), dim3(256), 0, stream,
                       pose_enc, app_pose, app_enc, qb, kb, vb, ws);

    // factored attention
    hipMemsetAsync((void*)(ws + S_OFF), 0, 32768 * sizeof(float), stream);
    hipLaunchKernelGGL(attn_S_k, dim3(8, 8), dim3(256), 0, stream, ws);
    hipLaunchKernelGGL(attn_O_k, dim3(64, 8), dim3(256), 0, stream, gamma, ws);

    // instance-norm accumulators (alias S region; S is dead after attn_O)
    hipMemsetAsync((void*)(ws + SUM_OFF), 0, 2048 * sizeof(float), stream);

    // 1x1 conv, 3x3 conv + partial sums, normalize
    hipLaunchKernelGGL(conv1x1_k, dim3(256, 4, 2), dim3(256), 0, stream, pose_enc, fb, ws);
    hipLaunchKernelGGL(conv3x3_k, dim3(256, 4, 2), dim3(256), 0, stream, prev_inp, cb, ws);
    hipLaunchKernelGGL(inorm_relu_k, dim3(512), dim3(256), 0, stream, ws, out);
}

// Round 2
// 495.415 us; speedup vs baseline: 3.6552x; 3.6552x over previous
//
#include <hip/hip_runtime.h>
#include <hip/hip_bf16.h>

// Problem constants
#define BB   2
#define CC   256
#define PCC  256
#define OCC  256
#define HH   128
#define WW   128
#define N2   4096    // 64*64 attn pixels
#define HWP  16384   // 128*128
#define EPSI 1e-5f

typedef unsigned short ushort_t;
typedef __attribute__((ext_vector_type(8))) short short8;
typedef __attribute__((ext_vector_type(4))) float f32x4;

// ---- workspace layout (float word offsets) ----
// Phase A (qkv/attn): Q,K,V,ATT,S live.
// Phase B (conv3x3): xcatT bf16 aliases Q..ATT (33.55MB), zeropage aliases S,
//                    y3 bf16 aliases X1, wA3 bf16 in old CWT slot.
static const size_t Q_OFF    = 0;          // 2,097,152 f32 each
static const size_t K_OFF    = 2097152;
static const size_t V_OFF    = 4194304;
static const size_t ATT_OFF  = 6291456;
static const size_t S_OFF    = 8388608;    // 32,768 f32 (attn scratch)
static const size_t ZP_OFF   = 8388608;    // 256B zero page (aliases S, after attn)
static const size_t X1_OFF   = 8421376;    // 8,388,608 f32  [B][256][16384]
static const size_t QWT_OFF  = 16809984;   // 262,144 f32 wT[k][oc]
static const size_t KWT_OFF  = 17072128;
static const size_t VWT_OFF  = 17334272;
static const size_t FWT_OFF  = 17596416;   // 131,072
static const size_t WA3_OFF  = 17727488;   // bf16 wA3[9][256][512] = 589,824 f32-slots
// end = 18,907,136 floats = 75.6 MB (same as round 1)
// xcatT bf16 [2][16384][512] = 16,777,216 ushort = byte 0..33,554,432 (aliases Q..ATT)
// y3 bf16 [2][256][16384] at X1_OFF (aliases X1, dead after xcat_k)

__device__ __forceinline__ ushort_t f2bf(float x) {
    union { float f; unsigned u; } v; v.f = x;
    unsigned r = v.u + 0x7FFFu + ((v.u >> 16) & 1u);
    return (ushort_t)(r >> 16);
}
__device__ __forceinline__ float bf2f(ushort_t h) {
    union { unsigned u; float f; } v; v.u = ((unsigned)h) << 16; return v.f;
}

__device__ __forceinline__ void gload_lds16(const void* g, void* l) {
    __builtin_amdgcn_global_load_lds(
        (const __attribute__((address_space(1))) void*)g,
        (__attribute__((address_space(3))) void*)l, 16, 0, 0);
}

// ---------------- weight transpose: wT[k][oc] = w[oc][k] ----------------
__global__ __launch_bounds__(256) void transpose_w(const float* __restrict__ w,
                                                   float* __restrict__ wT,
                                                   int M, int K) {
    int total = M * K;
    for (int idx = blockIdx.x * 256 + threadIdx.x; idx < total; idx += gridDim.x * 256) {
        int oc = idx / K, k = idx - oc * K;
        wT[k * M + oc] = w[idx];
    }
}

// ---------------- pack 3x3 weights tap-major bf16: wA3[t][oc][c] ----------
__global__ __launch_bounds__(256) void build_wA3(const float* __restrict__ cw,
                                                 ushort_t* __restrict__ wA3) {
    int idx = blockIdx.x * 256 + threadIdx.x;   // oc*512 + c, total 131072
    if (idx >= 131072) return;
    const float* src = cw + (size_t)idx * 9;
#pragma unroll
    for (int tp = 0; tp < 9; ++tp)
        wA3[(size_t)tp * 131072 + idx] = f2bf(src[tp]);
}

// 16-step K-chunk FMA micro-kernel (f32 path)
__device__ __forceinline__ void mm16(const float (*As)[64], const float (*Bs)[64],
                                     int ty, int tx, float acc[4][4]) {
#pragma unroll
    for (int kk = 0; kk < 16; ++kk) {
        float4 a4 = *(const float4*)&As[kk][ty * 4];
        float4 b4 = *(const float4*)&Bs[kk][tx * 4];
        float a[4] = {a4.x, a4.y, a4.z, a4.w};
        float b[4] = {b4.x, b4.y, b4.z, b4.w};
#pragma unroll
        for (int i = 0; i < 4; ++i)
#pragma unroll
            for (int j = 0; j < 4; ++j)
                acc[i][j] = fmaf(a[i], b[j], acc[i][j]);
    }
}

// ---------------- q/k/v stride-2 2x2 conv as GEMM (f32) ----------------
__global__ __launch_bounds__(256) void qkv_conv(
    const float* __restrict__ pose, const float* __restrict__ app_pose,
    const float* __restrict__ app,
    const float* __restrict__ qb, const float* __restrict__ kb,
    const float* __restrict__ vb, float* __restrict__ ws)
{
    int y2 = blockIdx.x;
    int oc0 = blockIdx.y * 64;
    int z = blockIdx.z;
    int b = z / 3, conv = z % 3;
    const float* in   = conv == 0 ? pose : (conv == 1 ? app_pose : app);
    const float* wT   = ws + (conv == 0 ? QWT_OFF : (conv == 1 ? KWT_OFF : VWT_OFF));
    const float* bias = conv == 0 ? qb : (conv == 1 ? kb : vb);
    float* out        = ws + (conv == 0 ? Q_OFF : (conv == 1 ? K_OFF : V_OFF));

    __shared__ float As[16][64];
    __shared__ float Bs[16][64];
    int t = threadIdx.x, ty = t >> 4, tx = t & 15;
    const float* inb = in + (size_t)b * CC * HH * WW;
    float acc[4][4] = {};

    for (int k0 = 0; k0 < 1024; k0 += 16) {
#pragma unroll
        for (int i = 0; i < 4; ++i) {
            int idx = t + i * 256;
            int kk = idx >> 6, ocl = idx & 63;
            As[kk][ocl] = wT[(size_t)(k0 + kk) * 256 + oc0 + ocl];
        }
#pragma unroll
        for (int i = 0; i < 4; ++i) {
            int idx = t + i * 256;
            int kk = idx >> 6, j = idx & 63;
            int k = k0 + kk;
            int c = k >> 2, fy = (k >> 1) & 1, fx = k & 1;
            Bs[kk][j] = inb[((size_t)c * HH + (2 * y2 + fy)) * WW + 2 * j + fx];
        }
        __syncthreads();
        mm16(As, Bs, ty, tx, acc);
        __syncthreads();
    }
#pragma unroll
    for (int i = 0; i < 4; ++i) {
        int oc = oc0 + ty * 4 + i;
        float bv = bias[oc];
        float4 r;
        r.x = acc[i][0] + bv; r.y = acc[i][1] + bv;
        r.z = acc[i][2] + bv; r.w = acc[i][3] + bv;
        *(float4*)&out[((size_t)b * 256 + oc) * N2 + y2 * 64 + tx * 4] = r;
    }
}

// ---------------- St[d'][d] = sum_m v[d,m]*k[d',m] ----------------
__global__ __launch_bounds__(256) void attn_S_k(float* __restrict__ ws)
{
    int mc = blockIdx.x;
    int bh = blockIdx.y;
    int b = bh >> 2, h = bh & 3;
    const float* vp = ws + V_OFF + (size_t)(b * 256 + h * 64) * N2;
    const float* kp = ws + K_OFF + (size_t)(b * 256 + h * 64) * N2;
    float* Sp = ws + S_OFF + (size_t)bh * 4096;

    __shared__ float VsT[16][64];
    __shared__ float KsT[16][64];
    int t = threadIdx.x, ty = t >> 4, tx = t & 15;
    int d_ = t >> 2;
    int mg = t & 3;
    float acc[4][4] = {};

    for (int m0 = mc * 512; m0 < mc * 512 + 512; m0 += 16) {
        float4 v4 = *(const float4*)&vp[(size_t)d_ * N2 + m0 + mg * 4];
        float4 k4 = *(const float4*)&kp[(size_t)d_ * N2 + m0 + mg * 4];
        VsT[mg * 4 + 0][d_] = v4.x; VsT[mg * 4 + 1][d_] = v4.y;
        VsT[mg * 4 + 2][d_] = v4.z; VsT[mg * 4 + 3][d_] = v4.w;
        KsT[mg * 4 + 0][d_] = k4.x; KsT[mg * 4 + 1][d_] = k4.y;
        KsT[mg * 4 + 2][d_] = k4.z; KsT[mg * 4 + 3][d_] = k4.w;
        __syncthreads();
        mm16(VsT, KsT, ty, tx, acc);
        __syncthreads();
    }
#pragma unroll
    for (int i = 0; i < 4; ++i)
#pragma unroll
        for (int j = 0; j < 4; ++j)
            atomicAdd(&Sp[(tx * 4 + j) * 64 + (ty * 4 + i)], acc[i][j]);
}

// ---------------- att[d][n] = gamma/8 * sum_d' St[d'][d] q[d'][n] ----------
__global__ __launch_bounds__(256) void attn_O_k(const float* __restrict__ gamma,
                                                float* __restrict__ ws)
{
    int n0 = blockIdx.x * 64;
    int bh = blockIdx.y;
    int b = bh >> 2, h = bh & 3;
    const float* Sp = ws + S_OFF + (size_t)bh * 4096;
    const float* qp = ws + Q_OFF + (size_t)(b * 256 + h * 64) * N2;
    float* op = ws + ATT_OFF + (size_t)(b * 256 + h * 64) * N2;
    float scale = gamma[h] * 0.125f;

    __shared__ float STs[64][64];
    __shared__ float Qs[16][64];
    int t = threadIdx.x, ty = t >> 4, tx = t & 15;
#pragma unroll
    for (int i = 0; i < 16; ++i) {
        int idx = t + i * 256;
        STs[idx >> 6][idx & 63] = Sp[idx];
    }
    float acc[4][4] = {};
    for (int d0 = 0; d0 < 64; d0 += 16) {
#pragma unroll
        for (int i = 0; i < 4; ++i) {
            int idx = t + i * 256;
            int dd = idx >> 6, j = idx & 63;
            Qs[dd][j] = qp[(size_t)(d0 + dd) * N2 + n0 + j];
        }
        __syncthreads();
#pragma unroll
        for (int dd = 0; dd < 16; ++dd) {
            float4 a4 = *(const float4*)&STs[d0 + dd][ty * 4];
            float4 q4 = *(const float4*)&Qs[dd][tx * 4];
            float a[4] = {a4.x, a4.y, a4.z, a4.w};
            float q[4] = {q4.x, q4.y, q4.z, q4.w};
#pragma unroll
            for (int i = 0; i < 4; ++i)
#pragma unroll
                for (int j = 0; j < 4; ++j)
                    acc[i][j] = fmaf(a[i], q[j], acc[i][j]);
        }
        __syncthreads();
    }
#pragma unroll
    for (int i = 0; i < 4; ++i) {
        float4 r;
        r.x = scale * acc[i][0]; r.y = scale * acc[i][1];
        r.z = scale * acc[i][2]; r.w = scale * acc[i][3];
        *(float4*)&op[(size_t)(ty * 4 + i) * N2 + n0 + tx * 4] = r;
    }
}

// ---------------- 1x1 conv over [pose ; upsampled att] (f32) -> X1 ---------
__global__ __launch_bounds__(256) void conv1x1_k(const float* __restrict__ pose,
                                                 const float* __restrict__ fb,
                                                 float* __restrict__ ws)
{
    int p0 = blockIdx.x * 64;
    int oc0 = blockIdx.y * 64;
    int b = blockIdx.z;
    int y = p0 >> 7, x0 = p0 & 127;
    const float* fwT = ws + FWT_OFF;
    const float* att = ws + ATT_OFF + (size_t)b * CC * N2;
    const float* pz  = pose + (size_t)b * CC * HWP;
    float* out = ws + X1_OFF + (size_t)b * CC * HWP;

    __shared__ float As[16][64];
    __shared__ float Bs[16][64];
    int t = threadIdx.x, ty = t >> 4, tx = t & 15;
    float acc[4][4] = {};

    for (int k0 = 0; k0 < 512; k0 += 16) {
#pragma unroll
        for (int i = 0; i < 4; ++i) {
            int idx = t + i * 256;
            int kk = idx >> 6, ocl = idx & 63;
            As[kk][ocl] = fwT[(size_t)(k0 + kk) * 256 + oc0 + ocl];
        }
#pragma unroll
        for (int i = 0; i < 4; ++i) {
            int idx = t + i * 256;
            int kk = idx >> 6, j = idx & 63;
            int k = k0 + kk;
            float v;
            if (k < 256) v = pz[(size_t)k * HWP + y * 128 + x0 + j];
            else         v = att[(size_t)(k - 256) * N2 + (y >> 1) * 64 + ((x0 + j) >> 1)];
            Bs[kk][j] = v;
        }
        __syncthreads();
        mm16(As, Bs, ty, tx, acc);
        __syncthreads();
    }
#pragma unroll
    for (int i = 0; i < 4; ++i) {
        int oc = oc0 + ty * 4 + i;
        float bv = fb[oc];
        float4 r;
        r.x = acc[i][0] + bv; r.y = acc[i][1] + bv;
        r.z = acc[i][2] + bv; r.w = acc[i][3] + bv;
        *(float4*)&out[(size_t)oc * HWP + y * 128 + x0 + tx * 4] = r;
    }
}

// ---------------- build pixel-major bf16 xcatT[b][px][512] ----------------
// ct<4: channels from X1 (f32, channel-major); ct>=4: upsampled prev.
__global__ __launch_bounds__(256) void xcat_k(const float* __restrict__ prev,
                                              float* __restrict__ wsf)
{
    int y = blockIdx.x, ct = blockIdx.y, b = blockIdx.z;
    int t = threadIdx.x;
    __shared__ ushort_t T[64][128];
    ushort_t* xcatT = (ushort_t*)wsf;

    if (ct < 4) {
        const float* x1 = wsf + X1_OFF + ((size_t)b * 256 + ct * 64) * HWP + (size_t)y * 128;
#pragma unroll
        for (int i = 0; i < 8; ++i) {
            int s = t + i * 256;            // 2048 float4 slots
            int cc = s >> 5, xq = s & 31;
            float4 v = *(const float4*)&x1[(size_t)cc * HWP + xq * 4];
            ushort_t h0 = f2bf(v.x), h1 = f2bf(v.y), h2 = f2bf(v.z), h3 = f2bf(v.w);
            ushort4 h = make_ushort4(h0, h1, h2, h3);
            *(ushort4*)&T[cc][xq * 4] = h;
        }
    } else {
        const float* pv = prev + ((size_t)b * 256 + (ct - 4) * 64) * N2 + (size_t)(y >> 1) * 64;
#pragma unroll
        for (int i = 0; i < 4; ++i) {
            int s = t + i * 256;            // 1024 float4 slots
            int cc = s >> 4, xq = s & 15;
            float4 v = *(const float4*)&pv[(size_t)cc * N2 + xq * 4];
            ushort4 h = make_ushort4(f2bf(v.x), f2bf(v.y), f2bf(v.z), f2bf(v.w));
            *(ushort4*)&T[cc][xq * 4] = h;
        }
    }
    __syncthreads();
    bool up = ct >= 4;
#pragma unroll
    for (int i = 0; i < 4; ++i) {
        int w = t * 4 + i;                  // 1024 slots of 8 channels
        int px = w >> 3, cbk = w & 7;
        int sx = up ? (px >> 1) : px;
        short8 o;
#pragma unroll
        for (int j = 0; j < 8; ++j) o[j] = (short)T[cbk * 8 + j][sx];
        *(short8*)&xcatT[(((size_t)b * HWP) + (size_t)y * 128 + px) * 512 + ct * 64 + cbk * 8] = o;
    }
}

// ---------------- 3x3 conv as bf16 MFMA GEMM ----------------
// grid 512 (XCD-swizzled -> b, oc-tile, row). BM=128, BN=128(one row), BK=64.
__global__ __launch_bounds__(256, 2) void conv3x3_mfma(const float* __restrict__ cb,
                                                       float* __restrict__ wsf)
{
    int lin = blockIdx.x;
    int swz = (lin & 7) * 64 + (lin >> 3);   // XCD-contiguous chunks (512%8==0)
    int y = swz & 127, oct = (swz >> 7) & 1, b = swz >> 8;
    int oc0 = oct * 128;

    const ushort_t* xcatT = (const ushort_t*)wsf;
    const ushort_t* wA3   = (const ushort_t*)(wsf + WA3_OFF);
    const ushort_t* zp    = (const ushort_t*)(wsf + ZP_OFF);
    ushort_t* y3          = (ushort_t*)(wsf + X1_OFF);

    __shared__ alignas(16) ushort_t As[128 * 64];
    __shared__ alignas(16) ushort_t Bs[128 * 64];

    int t = threadIdx.x;
    int lane = t & 63, wv = t >> 6;
    int wm = wv >> 1, wn = wv & 1;
    int l15 = lane & 15, lq = lane >> 4;

    f32x4 acc[4][4] = {};

    for (int chunk = 0; chunk < 72; ++chunk) {
        int tap = chunk >> 3, c0 = (chunk & 7) << 6;
        int fy = tap / 3, fx = tap % 3;
        int yy = y + fy - 1;
        // A tile: weights [128 oc][64 c], 16B blocks XOR-swizzled via source perm
#pragma unroll
        for (int r = 0; r < 4; ++r) {
            int slot = t + r * 256;
            int row = slot >> 3, cbk = slot & 7;
            const ushort_t* src = wA3 + (((size_t)tap * 256 + oc0 + row) * 512
                                         + c0 + ((cbk ^ (row & 7)) << 3));
            ushort_t* dst = (ushort_t*)As + (((size_t)wv * 64 + r * 256) << 3);
            gload_lds16(src, dst);
        }
        // B tile: im2col pixels [128 n][64 c], zero page for OOB
#pragma unroll
        for (int r = 0; r < 4; ++r) {
            int slot = t + r * 256;
            int n = slot >> 3, cbk = slot & 7;
            int xx = n + fx - 1;
            bool ok = (yy >= 0) && (yy < 128) && (xx >= 0) && (xx < 128);
            const ushort_t* src = ok
                ? xcatT + (((size_t)b * HWP + (size_t)yy * 128 + xx) * 512
                           + c0 + ((cbk ^ (n & 7)) << 3))
                : zp;
            ushort_t* dst = (ushort_t*)Bs + (((size_t)wv * 64 + r * 256) << 3);
            gload_lds16(src, dst);
        }
        __syncthreads();   // drains vmcnt -> LDS tiles ready
#pragma unroll
        for (int ks = 0; ks < 2; ++ks) {
            short8 af[4], bf[4];
#pragma unroll
            for (int m = 0; m < 4; ++m) {
                int row = wm * 64 + m * 16 + l15;
                int blk = (ks * 4 + lq) ^ (row & 7);
                af[m] = *(const short8*)&As[row * 64 + blk * 8];
            }
#pragma unroll
            for (int n = 0; n < 4; ++n) {
                int col = wn * 64 + n * 16 + l15;
                int blk = (ks * 4 + lq) ^ (col & 7);
                bf[n] = *(const short8*)&Bs[col * 64 + blk * 8];
            }
#pragma unroll
            for (int m = 0; m < 4; ++m)
#pragma unroll
                for (int n = 0; n < 4; ++n)
                    acc[m][n] = __builtin_amdgcn_mfma_f32_16x16x32_bf16(
                        af[m], bf[n], acc[m][n], 0, 0, 0);
        }
        __syncthreads();   // all reads done before next stage overwrites
    }

    // epilogue: bias + bf16 store (D: col=lane&15 -> pixel, row=(lane>>4)*4+reg -> oc)
    float bias[4][4];
#pragma unroll
    for (int m = 0; m < 4; ++m)
#pragma unroll
        for (int r = 0; r < 4; ++r)
            bias[m][r] = cb[oc0 + wm * 64 + m * 16 + lq * 4 + r];
#pragma unroll
    for (int m = 0; m < 4; ++m)
#pragma unroll
        for (int n = 0; n < 4; ++n) {
            int col = wn * 64 + n * 16 + l15;
            size_t pxo = (size_t)y * 128 + col;
#pragma unroll
            for (int r = 0; r < 4; ++r) {
                int oc = oc0 + wm * 64 + m * 16 + lq * 4 + r;
                y3[((size_t)b * 256 + oc) * HWP + pxo] = f2bf(acc[m][n][r] + bias[m][r]);
            }
        }
}

// ---------------- instance norm + relu: y3 bf16 -> f32 out ----------------
__global__ __launch_bounds__(256) void inorm_relu_k(const float* __restrict__ wsf,
                                                    float* __restrict__ out)
{
    int bc = blockIdx.x;   // b*256+oc
    const ushort_t* yp = (const ushort_t*)(wsf + X1_OFF) + (size_t)bc * HWP;
    int t = threadIdx.x;
    float s1 = 0.f, s2 = 0.f;
#pragma unroll
    for (int i = 0; i < 8; ++i) {
        short8 v = *(const short8*)&yp[(size_t)(t + i * 256) * 8];
#pragma unroll
        for (int j = 0; j < 8; ++j) {
            float f = bf2f((ushort_t)v[j]);
            s1 += f; s2 += f * f;
        }
    }
#pragma unroll
    for (int o = 32; o; o >>= 1) {
        s1 += __shfl_xor(s1, o, 64);
        s2 += __shfl_xor(s2, o, 64);
    }
    __shared__ float r1[4], r2[4];
    if ((t & 63) == 0) { r1[t >> 6] = s1; r2[t >> 6] = s2; }
    __syncthreads();
    float S1 = r1[0] + r1[1] + r1[2] + r1[3];
    float S2 = r2[0] + r2[1] + r2[2] + r2[3];
    float mean = S1 * (1.f / HWP);
    float var  = S2 * (1.f / HWP) - mean * mean;
    float inv  = rsqrtf(var + EPSI);
    float* op = out + (size_t)bc * HWP;
#pragma unroll
    for (int i = 0; i < 8; ++i) {
        int base = (t + i * 256) * 8;
        short8 v = *(const short8*)&yp[(size_t)base];
        float4 o0, o1;
        o0.x = fmaxf((bf2f((ushort_t)v[0]) - mean) * inv, 0.f);
        o0.y = fmaxf((bf2f((ushort_t)v[1]) - mean) * inv, 0.f);
        o0.z = fmaxf((bf2f((ushort_t)v[2]) - mean) * inv, 0.f);
        o0.w = fmaxf((bf2f((ushort_t)v[3]) - mean) * inv, 0.f);
        o1.x = fmaxf((bf2f((ushort_t)v[4]) - mean) * inv, 0.f);
        o1.y = fmaxf((bf2f((ushort_t)v[5]) - mean) * inv, 0.f);
        o1.z = fmaxf((bf2f((ushort_t)v[6]) - mean) * inv, 0.f);
        o1.w = fmaxf((bf2f((ushort_t)v[7]) - mean) * inv, 0.f);
        *(float4*)&op[base]     = o0;
        *(float4*)&op[base + 4] = o1;
    }
}

extern "C" void kernel_launch(void* const* d_in, const int* in_sizes, int n_in,
                              void* d_out, int out_size, void* d_ws, size_t ws_size,
                              hipStream_t stream)
{
    (void)in_sizes; (void)n_in; (void)out_size; (void)ws_size;
    const float* app_enc  = (const float*)d_in[0];
    const float* app_pose = (const float*)d_in[1];
    const float* pose_enc = (const float*)d_in[2];
    const float* prev_inp = (const float*)d_in[3];
    const float* qw = (const float*)d_in[4];
    const float* qb = (const float*)d_in[5];
    const float* kw = (const float*)d_in[6];
    const float* kb = (const float*)d_in[7];
    const float* vw = (const float*)d_in[8];
    const float* vb = (const float*)d_in[9];
    const float* gamma = (const float*)d_in[10];
    const float* fw = (const float*)d_in[11];
    const float* fb = (const float*)d_in[12];
    const float* cw = (const float*)d_in[13];
    const float* cb = (const float*)d_in[14];
    float* ws  = (float*)d_ws;
    float* out = (float*)d_out;

    // weight prep
    hipLaunchKernelGGL(transpose_w, dim3(512), dim3(256), 0, stream, qw, ws + QWT_OFF, 256, 1024);
    hipLaunchKernelGGL(transpose_w, dim3(512), dim3(256), 0, stream, kw, ws + KWT_OFF, 256, 1024);
    hipLaunchKernelGGL(transpose_w, dim3(512), dim3(256), 0, stream, vw, ws + VWT_OFF, 256, 1024);
    hipLaunchKernelGGL(transpose_w, dim3(512), dim3(256), 0, stream, fw, ws + FWT_OFF, 256, 512);
    hipLaunchKernelGGL(build_wA3, dim3(512), dim3(256), 0, stream, cw, (ushort_t*)(ws + WA3_OFF));

    // q/k/v projections (f32)
    hipLaunchKernelGGL(qkv_conv, dim3(64, 4, 6), dim3(256), 0, stream,
                       pose_enc, app_pose, app_enc, qb, kb, vb, ws);

    // factored attention (f32)
    hipMemsetAsync((void*)(ws + S_OFF), 0, 32768 * sizeof(float), stream);
    hipLaunchKernelGGL(attn_S_k, dim3(8, 8), dim3(256), 0, stream, ws);
    hipLaunchKernelGGL(attn_O_k, dim3(64, 8), dim3(256), 0, stream, gamma, ws);

    // 1x1 conv (f32) -> X1
    hipLaunchKernelGGL(conv1x1_k, dim3(256, 4, 2), dim3(256), 0, stream, pose_enc, fb, ws);

    // zero page for OOB rows/cols (aliases dead S region)
    hipMemsetAsync((void*)(ws + ZP_OFF), 0, 256, stream);

    // pixel-major bf16 concat input (aliases dead Q..ATT region)
    hipLaunchKernelGGL(xcat_k, dim3(128, 8, 2), dim3(256), 0, stream, prev_inp, ws);

    // 3x3 conv MFMA -> y3 bf16 (aliases dead X1)
    hipLaunchKernelGGL(conv3x3_mfma, dim3(512), dim3(256), 0, stream, cb, ws);

    // instance norm + relu -> f32 out
    hipLaunchKernelGGL(inorm_relu_k, dim3(512), dim3(256), 0, stream, ws, out);
}

// Round 3
// 245.546 us; speedup vs baseline: 7.3748x; 2.0176x over previous
//
#include <hip/hip_runtime.h>
#include <hip/hip_bf16.h>

#define N2   4096    // 64*64 attn pixels
#define HWP  16384   // 128*128
#define EPSI 1e-5f

typedef unsigned short ushort_t;
typedef __attribute__((ext_vector_type(8))) short short8;
typedef __attribute__((ext_vector_type(4))) float f32x4;

// ---- workspace layout (f32-word offsets), peak 14,450,752 words = 57.8 MB ----
static const size_t XPM_OFF   = 0;          // bf16 [2][16384][256] staged input (per conv); later y3 [2][256][16384]
static const size_t QT_OFF    = 4194304;    // bf16 [2][4096][256]  q pixel-major (gamma/8 folded)
static const size_t KC_OFF    = 5242880;    // bf16 [2][256][4096]  k channel-major; later attT [2][4096][256]
static const size_t VC_OFF    = 6291456;    // bf16 [2][256][4096]  v channel-major
static const size_t S_OFF     = 7340032;    // f32  [8][64][64]
static const size_t XCAT_OFF  = 7372800;    // bf16 [2][16384][256] conv1x1 out pixel-major
static const size_t PREVT_OFF = 11567104;   // bf16 [2][4096][256]  prev pixel-major (not upsampled)
static const size_t WQ_OFF    = 12615680;   // bf16 [4][256][256]
static const size_t WK_OFF    = 13008896;
static const size_t WV_OFF    = 13402112;
static const size_t WF_OFF    = 13795328;   // bf16 [256][512]
static const size_t WA3_OFF   = 13860864;   // bf16 [9][256][512]
static const size_t ZP_OFF    = 14450688;   // 64 words zero page

__device__ __forceinline__ ushort_t f2bf(float x) {
    union { float f; unsigned u; } v; v.f = x;
    unsigned r = v.u + 0x7FFFu + ((v.u >> 16) & 1u);
    return (ushort_t)(r >> 16);
}
__device__ __forceinline__ float bf2f(ushort_t h) {
    union { unsigned u; float f; } v; v.u = ((unsigned)h) << 16; return v.f;
}
__device__ __forceinline__ void gload_lds16(const void* g, void* l) {
    __builtin_amdgcn_global_load_lds(
        (const __attribute__((address_space(1))) void*)g,
        (__attribute__((address_space(3))) void*)l, 16, 0, 0);
}

// ---------------- weight packs ----------------
// qkv: [oc=256][c=256][2][2] f32 -> wA[tap][oc][c] bf16
__global__ __launch_bounds__(256) void pack_wqkv(const float* __restrict__ qw,
                                                 const float* __restrict__ kw,
                                                 const float* __restrict__ vw,
                                                 float* __restrict__ wsf) {
    int conv = blockIdx.y;
    int idx = blockIdx.x * 256 + threadIdx.x;   // oc*256 + c, 65536 total
    const float* src = conv == 0 ? qw : (conv == 1 ? kw : vw);
    ushort_t* dst = (ushort_t*)(wsf + (conv == 0 ? WQ_OFF : (conv == 1 ? WK_OFF : WV_OFF)));
    float4 v = *(const float4*)&src[(size_t)idx * 4];
    dst[0 * 65536 + idx] = f2bf(v.x);
    dst[1 * 65536 + idx] = f2bf(v.y);
    dst[2 * 65536 + idx] = f2bf(v.z);
    dst[3 * 65536 + idx] = f2bf(v.w);
}

__global__ __launch_bounds__(256) void pack_wf(const float* __restrict__ fw,
                                               float* __restrict__ wsf) {
    int idx = blockIdx.x * 256 + threadIdx.x;   // 131072
    ((ushort_t*)(wsf + WF_OFF))[idx] = f2bf(fw[idx]);
}

// cw [256][512][3][3] -> wA3[tap][oc][512c] bf16
__global__ __launch_bounds__(256) void build_wA3(const float* __restrict__ cw,
                                                 float* __restrict__ wsf) {
    int idx = blockIdx.x * 256 + threadIdx.x;   // oc*512 + c, 131072
    ushort_t* wA3 = (ushort_t*)(wsf + WA3_OFF);
    const float* src = cw + (size_t)idx * 9;
#pragma unroll
    for (int tp = 0; tp < 9; ++tp)
        wA3[(size_t)tp * 131072 + idx] = f2bf(src[tp]);
}

// ---------------- input transposes to pixel-major bf16 ----------------
// in [b][256][128][128] f32 -> xpm [b][16384 px][256 c] bf16
__global__ __launch_bounds__(256) void xpm_k(const float* __restrict__ in,
                                             float* __restrict__ wsf) {
    int y = blockIdx.x, ct = blockIdx.y, b = blockIdx.z;
    int t = threadIdx.x;
    __shared__ ushort_t T[64][128];
    ushort_t* xpm = (ushort_t*)(wsf + XPM_OFF);
#pragma unroll
    for (int i = 0; i < 8; ++i) {
        int s = t + i * 256;                   // 2048 float4 slots
        int cc = s >> 5, xq = s & 31;
        float4 v = *(const float4*)&in[(((size_t)b * 256 + ct * 64 + cc) * 128 + y) * 128 + xq * 4];
        ushort4 h; h.x = f2bf(v.x); h.y = f2bf(v.y); h.z = f2bf(v.z); h.w = f2bf(v.w);
        *(ushort4*)&T[cc][xq * 4] = h;
    }
    __syncthreads();
#pragma unroll
    for (int i = 0; i < 4; ++i) {
        int w = t * 4 + i;                     // 1024 short8 slots
        int px = w >> 3, cbk = w & 7;
        short8 o;
#pragma unroll
        for (int j = 0; j < 8; ++j) o[j] = (short)T[cbk * 8 + j][px];
        *(short8*)&xpm[(((size_t)b * HWP) + (size_t)y * 128 + px) * 256 + ct * 64 + cbk * 8] = o;
    }
}

// prev [b][256][64][64] f32 -> prevT [b][4096 px][256 c] bf16
__global__ __launch_bounds__(256) void prevT_k(const float* __restrict__ prev,
                                               float* __restrict__ wsf) {
    int y2 = blockIdx.x, ct = blockIdx.y, b = blockIdx.z;
    int t = threadIdx.x;
    __shared__ ushort_t T[64][64];
    ushort_t* pT = (ushort_t*)(wsf + PREVT_OFF);
#pragma unroll
    for (int i = 0; i < 4; ++i) {
        int s = t + i * 256;                   // 1024 float4 slots
        int cc = s >> 4, xq = s & 15;
        float4 v = *(const float4*)&prev[(((size_t)b * 256 + ct * 64 + cc) * 64 + y2) * 64 + xq * 4];
        ushort4 h; h.x = f2bf(v.x); h.y = f2bf(v.y); h.z = f2bf(v.z); h.w = f2bf(v.w);
        *(ushort4*)&T[cc][xq * 4] = h;
    }
    __syncthreads();
#pragma unroll
    for (int i = 0; i < 2; ++i) {
        int w = t * 2 + i;                     // 512 short8 slots
        int px = w >> 3, cbk = w & 7;
        short8 o;
#pragma unroll
        for (int j = 0; j < 8; ++j) o[j] = (short)T[cbk * 8 + j][px];
        *(short8*)&pT[((size_t)b * N2 + (size_t)y2 * 64 + px) * 256 + ct * 64 + cbk * 8] = o;
    }
}

// ---------------- qkv stride-2 2x2 conv as bf16 MFMA GEMM ----------------
// grid (64 nb, 2 oct, 2 b). BM=128, BN=64, BK=64, 16 chunks (4 taps x 4 c-chunks).
// MODE 0: q -> pixel-major qT, scaled by gamma[h]/8.  MODE 1: k/v -> channel-major.
template<int MODE>
__global__ __launch_bounds__(256) void qkv_mfma(const float* __restrict__ bias,
                                                const float* __restrict__ gamma,
                                                const ushort_t* __restrict__ wA,
                                                const ushort_t* __restrict__ xpm,
                                                ushort_t* __restrict__ outp) {
    int nb = blockIdx.x, oct = blockIdx.y, b = blockIdx.z;
    int n0 = nb * 64, oc0 = oct * 128;
    __shared__ alignas(16) ushort_t As[128 * 64];
    __shared__ alignas(16) ushort_t Bs[64 * 64];
    int t = threadIdx.x, lane = t & 63, wv = t >> 6;
    int wm = wv >> 1, wn = wv & 1, l15 = lane & 15, lq = lane >> 4;
    f32x4 acc[4][2] = {};

    for (int chunk = 0; chunk < 16; ++chunk) {
        int tap = chunk >> 2, c0 = (chunk & 3) << 6;
        int fy = tap >> 1, fx = tap & 1;
#pragma unroll
        for (int r = 0; r < 4; ++r) {          // A: 1024 slots
            int slot = t + r * 256;
            int row = slot >> 3, cbk = slot & 7;
            const ushort_t* src = wA + ((size_t)tap * 65536 + (size_t)(oc0 + row) * 256
                                        + c0 + ((cbk ^ (row & 7)) << 3));
            gload_lds16(src, (ushort_t*)As + (((size_t)wv * 64 + r * 256) << 3));
        }
#pragma unroll
        for (int r = 0; r < 2; ++r) {          // B: 512 slots
            int slot = t + r * 256;
            int n = slot >> 3, cbk = slot & 7;
            int ng = n0 + n;
            int iy = ((ng >> 6) << 1) + fy, ix = ((ng & 63) << 1) + fx;
            const ushort_t* src = xpm + (((size_t)b * HWP + (size_t)iy * 128 + ix) * 256
                                         + c0 + ((cbk ^ (n & 7)) << 3));
            gload_lds16(src, (ushort_t*)Bs + (((size_t)wv * 64 + r * 256) << 3));
        }
        __syncthreads();
#pragma unroll
        for (int ks = 0; ks < 2; ++ks) {
            short8 af[4], bf[2];
#pragma unroll
            for (int m = 0; m < 4; ++m) {
                int row = wm * 64 + m * 16 + l15;
                int blk = (ks * 4 + lq) ^ (row & 7);
                af[m] = *(const short8*)&As[row * 64 + blk * 8];
            }
#pragma unroll
            for (int n = 0; n < 2; ++n) {
                int col = wn * 32 + n * 16 + l15;
                int blk = (ks * 4 + lq) ^ (col & 7);
                bf[n] = *(const short8*)&Bs[col * 64 + blk * 8];
            }
#pragma unroll
            for (int m = 0; m < 4; ++m)
#pragma unroll
                for (int n = 0; n < 2; ++n)
                    acc[m][n] = __builtin_amdgcn_mfma_f32_16x16x32_bf16(
                        af[m], bf[n], acc[m][n], 0, 0, 0);
        }
        __syncthreads();
    }
#pragma unroll
    for (int m = 0; m < 4; ++m)
#pragma unroll
        for (int n = 0; n < 2; ++n) {
            int col = wn * 32 + n * 16 + l15;
            int ng = n0 + col;
            int ocq = oc0 + wm * 64 + m * 16 + lq * 4;
            if (MODE == 0) {
                ushort4 o;
                float s0 = gamma[ocq >> 6] * 0.125f;   // quad stays in one head (ocq%64<=60)
                o.x = f2bf((acc[m][n][0] + bias[ocq + 0]) * s0);
                o.y = f2bf((acc[m][n][1] + bias[ocq + 1]) * s0);
                o.z = f2bf((acc[m][n][2] + bias[ocq + 2]) * s0);
                o.w = f2bf((acc[m][n][3] + bias[ocq + 3]) * s0);
                *(ushort4*)&outp[((size_t)b * N2 + ng) * 256 + ocq] = o;
            } else {
#pragma unroll
                for (int r = 0; r < 4; ++r)
                    outp[((size_t)(b * 256 + ocq + r)) * N2 + ng] =
                        f2bf(acc[m][n][r] + bias[ocq + r]);
            }
        }
}

// ---------------- S[d][d'] = sum_m v[d][m] k[d'][m]  (MFMA, atomic f32) ------
// grid (8 m-chunks, 8 bh), block 64 (one wave)
__global__ __launch_bounds__(64) void attn_S_mfma(float* __restrict__ wsf) {
    int mc = blockIdx.x, bh = blockIdx.y;
    int b = bh >> 2, h = bh & 3;
    const ushort_t* vp = (const ushort_t*)(wsf + VC_OFF) + (size_t)(b * 256 + h * 64) * N2;
    const ushort_t* kp = (const ushort_t*)(wsf + KC_OFF) + (size_t)(b * 256 + h * 64) * N2;
    float* Sp = wsf + S_OFF + (size_t)bh * 4096;
    int lane = threadIdx.x, l15 = lane & 15, lq = lane >> 4;
    f32x4 acc[4][4] = {};
    for (int m0 = mc * 512; m0 < mc * 512 + 512; m0 += 32) {
        short8 af[4], bf[4];
#pragma unroll
        for (int mt = 0; mt < 4; ++mt)
            af[mt] = *(const short8*)&vp[(size_t)(mt * 16 + l15) * N2 + m0 + lq * 8];
#pragma unroll
        for (int nt = 0; nt < 4; ++nt)
            bf[nt] = *(const short8*)&kp[(size_t)(nt * 16 + l15) * N2 + m0 + lq * 8];
#pragma unroll
        for (int mt = 0; mt < 4; ++mt)
#pragma unroll
            for (int nt = 0; nt < 4; ++nt)
                acc[mt][nt] = __builtin_amdgcn_mfma_f32_16x16x32_bf16(
                    af[mt], bf[nt], acc[mt][nt], 0, 0, 0);
    }
#pragma unroll
    for (int mt = 0; mt < 4; ++mt)
#pragma unroll
        for (int nt = 0; nt < 4; ++nt)
#pragma unroll
            for (int r = 0; r < 4; ++r)
                atomicAdd(&Sp[(mt * 16 + lq * 4 + r) * 64 + nt * 16 + l15], acc[mt][nt][r]);
}

// ---------------- attT[n][h*64+d] = sum_d' S[d][d'] qT[n][h*64+d'] ----------
// grid (16 nb, 8 bh), block 256 (4 waves, 64 n each)
__global__ __launch_bounds__(256) void attn_O_mfma(float* __restrict__ wsf) {
    int nb = blockIdx.x, bh = blockIdx.y;
    int b = bh >> 2, h = bh & 3;
    const float* Sp = wsf + S_OFF + (size_t)bh * 4096;
    const ushort_t* qT = (const ushort_t*)(wsf + QT_OFF);
    ushort_t* attT = (ushort_t*)(wsf + KC_OFF);
    __shared__ ushort_t Sl[64][72];
    int t = threadIdx.x;
#pragma unroll
    for (int g = 0; g < 4; ++g) {
        int idx = t * 16 + g * 4;
        float4 v = *(const float4*)&Sp[idx];
        int row = idx >> 6, col = idx & 63;
        ushort4 o; o.x = f2bf(v.x); o.y = f2bf(v.y); o.z = f2bf(v.z); o.w = f2bf(v.w);
        *(ushort4*)&Sl[row][col] = o;
    }
    __syncthreads();
    int lane = t & 63, wv = t >> 6, l15 = lane & 15, lq = lane >> 4;
    int n_base = nb * 256 + wv * 64;
    f32x4 acc[4][4] = {};
#pragma unroll
    for (int ks = 0; ks < 2; ++ks) {
        short8 aS[4], bq[4];
#pragma unroll
        for (int mt = 0; mt < 4; ++mt)
            aS[mt] = *(const short8*)&Sl[mt * 16 + l15][ks * 32 + lq * 8];
#pragma unroll
        for (int nt = 0; nt < 4; ++nt)
            bq[nt] = *(const short8*)&qT[((size_t)b * N2 + n_base + nt * 16 + l15) * 256
                                         + h * 64 + ks * 32 + lq * 8];
#pragma unroll
        for (int mt = 0; mt < 4; ++mt)
#pragma unroll
            for (int nt = 0; nt < 4; ++nt)
                acc[mt][nt] = __builtin_amdgcn_mfma_f32_16x16x32_bf16(
                    aS[mt], bq[nt], acc[mt][nt], 0, 0, 0);
    }
#pragma unroll
    for (int mt = 0; mt < 4; ++mt)
#pragma unroll
        for (int nt = 0; nt < 4; ++nt) {
            int n = n_base + nt * 16 + l15;
            ushort4 o;
            o.x = f2bf(acc[mt][nt][0]); o.y = f2bf(acc[mt][nt][1]);
            o.z = f2bf(acc[mt][nt][2]); o.w = f2bf(acc[mt][nt][3]);
            *(ushort4*)&attT[((size_t)b * N2 + n) * 256 + h * 64 + mt * 16 + lq * 4] = o;
        }
}

// ---------------- 1x1 conv as bf16 MFMA GEMM -> xcatT pixel-major ----------
// grid 512 swizzled. BM=128, BN=128 (one image row), K=512 (8 chunks).
__global__ __launch_bounds__(256, 2) void conv1x1_mfma(const float* __restrict__ fb,
                                                       float* __restrict__ wsf) {
    int lin = blockIdx.x;
    int swz = (lin & 7) * 64 + (lin >> 3);
    int y = swz & 127, oct = (swz >> 7) & 1, b = swz >> 8;
    int oc0 = oct * 128;
    const ushort_t* wF   = (const ushort_t*)(wsf + WF_OFF);
    const ushort_t* xpm  = (const ushort_t*)(wsf + XPM_OFF);   // pose pixel-major
    const ushort_t* attT = (const ushort_t*)(wsf + KC_OFF);
    ushort_t* xcatT      = (ushort_t*)(wsf + XCAT_OFF);

    __shared__ alignas(16) ushort_t As[128 * 64];
    __shared__ alignas(16) ushort_t Bs[128 * 64];
    int t = threadIdx.x, lane = t & 63, wv = t >> 6;
    int wm = wv >> 1, wn = wv & 1, l15 = lane & 15, lq = lane >> 4;
    f32x4 acc[4][4] = {};

    for (int chunk = 0; chunk < 8; ++chunk) {
        int c0 = chunk << 6;
#pragma unroll
        for (int r = 0; r < 4; ++r) {
            int slot = t + r * 256;
            int row = slot >> 3, cbk = slot & 7;
            const ushort_t* src = wF + ((size_t)(oc0 + row) * 512 + c0 + ((cbk ^ (row & 7)) << 3));
            gload_lds16(src, (ushort_t*)As + (((size_t)wv * 64 + r * 256) << 3));
        }
#pragma unroll
        for (int r = 0; r < 4; ++r) {
            int slot = t + r * 256;
            int n = slot >> 3, cbk = slot & 7;
            int sw = (cbk ^ (n & 7)) << 3;
            const ushort_t* src;
            if (c0 < 256)
                src = xpm + (((size_t)b * HWP + (size_t)y * 128 + n) * 256 + c0 + sw);
            else
                src = attT + (((size_t)b * N2 + (size_t)(y >> 1) * 64 + (n >> 1)) * 256
                              + (c0 - 256) + sw);
            gload_lds16(src, (ushort_t*)Bs + (((size_t)wv * 64 + r * 256) << 3));
        }
        __syncthreads();
#pragma unroll
        for (int ks = 0; ks < 2; ++ks) {
            short8 af[4], bf[4];
#pragma unroll
            for (int m = 0; m < 4; ++m) {
                int row = wm * 64 + m * 16 + l15;
                int blk = (ks * 4 + lq) ^ (row & 7);
                af[m] = *(const short8*)&As[row * 64 + blk * 8];
            }
#pragma unroll
            for (int n = 0; n < 4; ++n) {
                int col = wn * 64 + n * 16 + l15;
                int blk = (ks * 4 + lq) ^ (col & 7);
                bf[n] = *(const short8*)&Bs[col * 64 + blk * 8];
            }
#pragma unroll
            for (int m = 0; m < 4; ++m)
#pragma unroll
                for (int n = 0; n < 4; ++n)
                    acc[m][n] = __builtin_amdgcn_mfma_f32_16x16x32_bf16(
                        af[m], bf[n], acc[m][n], 0, 0, 0);
        }
        __syncthreads();
    }
#pragma unroll
    for (int m = 0; m < 4; ++m)
#pragma unroll
        for (int n = 0; n < 4; ++n) {
            int col = wn * 64 + n * 16 + l15;
            int ocq = oc0 + wm * 64 + m * 16 + lq * 4;
            ushort4 o;
            o.x = f2bf(acc[m][n][0] + fb[ocq + 0]);
            o.y = f2bf(acc[m][n][1] + fb[ocq + 1]);
            o.z = f2bf(acc[m][n][2] + fb[ocq + 2]);
            o.w = f2bf(acc[m][n][3] + fb[ocq + 3]);
            *(ushort4*)&xcatT[((size_t)b * HWP + (size_t)y * 128 + col) * 256 + ocq] = o;
        }
}

// ---------------- 3x3 SAME conv as bf16 MFMA GEMM -> y3 ----------------
// grid 512 swizzled. BM=128, BN=128 (one row), K=4608 (72 chunks).
__global__ __launch_bounds__(256, 2) void conv3x3_mfma(const float* __restrict__ cb,
                                                       float* __restrict__ wsf) {
    int lin = blockIdx.x;
    int swz = (lin & 7) * 64 + (lin >> 3);
    int y = swz & 127, oct = (swz >> 7) & 1, b = swz >> 8;
    int oc0 = oct * 128;

    const ushort_t* xcatT = (const ushort_t*)(wsf + XCAT_OFF);
    const ushort_t* prevT = (const ushort_t*)(wsf + PREVT_OFF);
    const ushort_t* wA3   = (const ushort_t*)(wsf + WA3_OFF);
    const ushort_t* zp    = (const ushort_t*)(wsf + ZP_OFF);
    ushort_t* y3          = (ushort_t*)(wsf + XPM_OFF);

    __shared__ alignas(16) ushort_t As[128 * 64];
    __shared__ alignas(16) ushort_t Bs[128 * 64];
    int t = threadIdx.x, lane = t & 63, wv = t >> 6;
    int wm = wv >> 1, wn = wv & 1, l15 = lane & 15, lq = lane >> 4;
    f32x4 acc[4][4] = {};

    for (int chunk = 0; chunk < 72; ++chunk) {
        int tap = chunk >> 3, c0 = (chunk & 7) << 6;
        int fy = tap / 3, fx = tap % 3;
        int yy = y + fy - 1;
#pragma unroll
        for (int r = 0; r < 4; ++r) {
            int slot = t + r * 256;
            int row = slot >> 3, cbk = slot & 7;
            const ushort_t* src = wA3 + (((size_t)tap * 256 + oc0 + row) * 512
                                         + c0 + ((cbk ^ (row & 7)) << 3));
            gload_lds16(src, (ushort_t*)As + (((size_t)wv * 64 + r * 256) << 3));
        }
#pragma unroll
        for (int r = 0; r < 4; ++r) {
            int slot = t + r * 256;
            int n = slot >> 3, cbk = slot & 7;
            int xx = n + fx - 1;
            int sw = (cbk ^ (n & 7)) << 3;
            bool ok = (yy >= 0) && (yy < 128) && (xx >= 0) && (xx < 128);
            const ushort_t* src;
            if (!ok)            src = zp;
            else if (c0 < 256)  src = xcatT + (((size_t)b * HWP + (size_t)yy * 128 + xx) * 256 + c0 + sw);
            else                src = prevT + (((size_t)b * N2 + (size_t)(yy >> 1) * 64 + (xx >> 1)) * 256
                                               + (c0 - 256) + sw);
            gload_lds16(src, (ushort_t*)Bs + (((size_t)wv * 64 + r * 256) << 3));
        }
        __syncthreads();
#pragma unroll
        for (int ks = 0; ks < 2; ++ks) {
            short8 af[4], bf[4];
#pragma unroll
            for (int m = 0; m < 4; ++m) {
                int row = wm * 64 + m * 16 + l15;
                int blk = (ks * 4 + lq) ^ (row & 7);
                af[m] = *(const short8*)&As[row * 64 + blk * 8];
            }
#pragma unroll
            for (int n = 0; n < 4; ++n) {
                int col = wn * 64 + n * 16 + l15;
                int blk = (ks * 4 + lq) ^ (col & 7);
                bf[n] = *(const short8*)&Bs[col * 64 + blk * 8];
            }
#pragma unroll
            for (int m = 0; m < 4; ++m)
#pragma unroll
                for (int n = 0; n < 4; ++n)
                    acc[m][n] = __builtin_amdgcn_mfma_f32_16x16x32_bf16(
                        af[m], bf[n], acc[m][n], 0, 0, 0);
        }
        __syncthreads();
    }
    // epilogue: bias + bf16 store channel-major y3[b][oc][px]
#pragma unroll
    for (int m = 0; m < 4; ++m)
#pragma unroll
        for (int n = 0; n < 4; ++n) {
            int col = wn * 64 + n * 16 + l15;
            size_t pxo = (size_t)y * 128 + col;
#pragma unroll
            for (int r = 0; r < 4; ++r) {
                int oc = oc0 + wm * 64 + m * 16 + lq * 4 + r;
                y3[((size_t)b * 256 + oc) * HWP + pxo] = f2bf(acc[m][n][r] + cb[oc]);
            }
        }
}

// ---------------- instance norm + relu: y3 bf16 -> f32 out ----------------
__global__ __launch_bounds__(256) void inorm_relu_k(const float* __restrict__ wsf,
                                                    float* __restrict__ out) {
    int bc = blockIdx.x;   // b*256+oc
    const ushort_t* yp = (const ushort_t*)(wsf + XPM_OFF) + (size_t)bc * HWP;
    int t = threadIdx.x;
    float s1 = 0.f, s2 = 0.f;
#pragma unroll
    for (int i = 0; i < 8; ++i) {
        short8 v = *(const short8*)&yp[(size_t)(t + i * 256) * 8];
#pragma unroll
        for (int j = 0; j < 8; ++j) {
            float f = bf2f((ushort_t)v[j]);
            s1 += f; s2 += f * f;
        }
    }
#pragma unroll
    for (int o = 32; o; o >>= 1) {
        s1 += __shfl_xor(s1, o, 64);
        s2 += __shfl_xor(s2, o, 64);
    }
    __shared__ float r1[4], r2[4];
    if ((t & 63) == 0) { r1[t >> 6] = s1; r2[t >> 6] = s2; }
    __syncthreads();
    float S1 = r1[0] + r1[1] + r1[2] + r1[3];
    float S2 = r2[0] + r2[1] + r2[2] + r2[3];
    float mean = S1 * (1.f / HWP);
    float var  = S2 * (1.f / HWP) - mean * mean;
    float inv  = rsqrtf(var + EPSI);
    float* op = out + (size_t)bc * HWP;
#pragma unroll
    for (int i = 0; i < 8; ++i) {
        int base = (t + i * 256) * 8;
        short8 v = *(const short8*)&yp[(size_t)base];
        float4 o0, o1;
        o0.x = fmaxf((bf2f((ushort_t)v[0]) - mean) * inv, 0.f);
        o0.y = fmaxf((bf2f((ushort_t)v[1]) - mean) * inv, 0.f);
        o0.z = fmaxf((bf2f((ushort_t)v[2]) - mean) * inv, 0.f);
        o0.w = fmaxf((bf2f((ushort_t)v[3]) - mean) * inv, 0.f);
        o1.x = fmaxf((bf2f((ushort_t)v[4]) - mean) * inv, 0.f);
        o1.y = fmaxf((bf2f((ushort_t)v[5]) - mean) * inv, 0.f);
        o1.z = fmaxf((bf2f((ushort_t)v[6]) - mean) * inv, 0.f);
        o1.w = fmaxf((bf2f((ushort_t)v[7]) - mean) * inv, 0.f);
        *(float4*)&op[base]     = o0;
        *(float4*)&op[base + 4] = o1;
    }
}

extern "C" void kernel_launch(void* const* d_in, const int* in_sizes, int n_in,
                              void* d_out, int out_size, void* d_ws, size_t ws_size,
                              hipStream_t stream)
{
    (void)in_sizes; (void)n_in; (void)out_size; (void)ws_size;
    const float* app_enc  = (const float*)d_in[0];
    const float* app_pose = (const float*)d_in[1];
    const float* pose_enc = (const float*)d_in[2];
    const float* prev_inp = (const float*)d_in[3];
    const float* qw = (const float*)d_in[4];
    const float* qb = (const float*)d_in[5];
    const float* kw = (const float*)d_in[6];
    const float* kb = (const float*)d_in[7];
    const float* vw = (const float*)d_in[8];
    const float* vb = (const float*)d_in[9];
    const float* gamma = (const float*)d_in[10];
    const float* fw = (const float*)d_in[11];
    const float* fb = (const float*)d_in[12];
    const float* cw = (const float*)d_in[13];
    const float* cb = (const float*)d_in[14];
    float* ws  = (float*)d_ws;
    float* out = (float*)d_out;

    const ushort_t* wQ = (const ushort_t*)(ws + WQ_OFF);
    const ushort_t* wK = (const ushort_t*)(ws + WK_OFF);
    const ushort_t* wV = (const ushort_t*)(ws + WV_OFF);
    const ushort_t* xpm = (const ushort_t*)(ws + XPM_OFF);
    ushort_t* qT = (ushort_t*)(ws + QT_OFF);
    ushort_t* kC = (ushort_t*)(ws + KC_OFF);
    ushort_t* vC = (ushort_t*)(ws + VC_OFF);

    // weight packs + prev transpose
    pack_wqkv<<<dim3(256, 3), 256, 0, stream>>>(qw, kw, vw, ws);
    pack_wf<<<512, 256, 0, stream>>>(fw, ws);
    build_wA3<<<512, 256, 0, stream>>>(cw, ws);
    prevT_k<<<dim3(64, 4, 2), 256, 0, stream>>>(prev_inp, ws);
    hipMemsetAsync((void*)(ws + S_OFF), 0, 32768 * sizeof(float), stream);
    hipMemsetAsync((void*)(ws + ZP_OFF), 0, 256, stream);

    // v, k, q projections (pose staged last: conv1x1 reads it)
    xpm_k<<<dim3(128, 4, 2), 256, 0, stream>>>(app_enc, ws);
    qkv_mfma<1><<<dim3(64, 2, 2), 256, 0, stream>>>(vb, gamma, wV, xpm, vC);
    xpm_k<<<dim3(128, 4, 2), 256, 0, stream>>>(app_pose, ws);
    qkv_mfma<1><<<dim3(64, 2, 2), 256, 0, stream>>>(kb, gamma, wK, xpm, kC);
    xpm_k<<<dim3(128, 4, 2), 256, 0, stream>>>(pose_enc, ws);
    qkv_mfma<0><<<dim3(64, 2, 2), 256, 0, stream>>>(qb, gamma, wQ, xpm, qT);

    // factored attention (MFMA)
    attn_S_mfma<<<dim3(8, 8), 64, 0, stream>>>(ws);
    attn_O_mfma<<<dim3(16, 8), 256, 0, stream>>>(ws);

    // 1x1 conv -> xcatT pixel-major; 3x3 conv -> y3; instance norm
    conv1x1_mfma<<<512, 256, 0, stream>>>(fb, ws);
    conv3x3_mfma<<<512, 256, 0, stream>>>(cb, ws);
    inorm_relu_k<<<512, 256, 0, stream>>>(ws, out);
}